// Round 5
// baseline (977.347 us; speedup 1.0000x reference)
//
#include <hip/hip_runtime.h>
#include <cstddef>
#include <cstdint>

// ---------------------------------------------------------------------------
// Swin block. f32 in/out; internal bf16 MFMA. B=8 H=W=64 DIM=512 NH=16 HD=32.
// GEMMs read operands DIRECTLY from global (L2-resident) into MFMA fragments:
// no LDS, no __syncthreads, no vmcnt(0) barrier drain in the K-loop.
// ws: [0,6.3M) bf16 weights | q[8,40) k[40,72) v[72,104) MB
//     h2 overlays q after proj; gbuf (32768x2048 bf16 split 2x64MB) over k+v.
// xw (LN1+shift, bf16 32MB) lives in d_out (dead until proj overwrites it).
// ---------------------------------------------------------------------------

typedef unsigned short u16;
typedef __attribute__((ext_vector_type(8))) short short8;
typedef __attribute__((ext_vector_type(4))) float floatx4;

__device__ __forceinline__ float bf2f(u16 u) {
    union { float f; unsigned i; } w; w.i = ((unsigned)u) << 16; return w.f;
}
__device__ __forceinline__ u16 f2bf(float f) {
    union { float f; unsigned i; } w; w.f = f;
    unsigned r = w.i + 0x7FFF + ((w.i >> 16) & 1);   // RNE
    return (u16)(r >> 16);
}

__device__ __forceinline__ int win_to_img_row(int t) {
    int win = t >> 6, n = t & 63;
    int b = win >> 6, wr = (win >> 3) & 7, wc = win & 7;
    int h = ((wr << 3) + (n >> 3) + 4) & 63;
    int w = ((wc << 3) + (n & 7) + 4) & 63;
    return (b << 12) + (h << 6) + w;
}

// ---------------------------------------------------------------------------
// Fused LayerNorm: one wave per 512-dim row, single pass.
// gather=1: row t reads shifted/windowed source row.
// ---------------------------------------------------------------------------
__global__ __launch_bounds__(256) void ln_fused(
    const float* __restrict__ x, const float* __restrict__ g,
    const float* __restrict__ b, u16* __restrict__ out, int gather)
{
    int wave = threadIdx.x >> 6, lane = threadIdx.x & 63;
    int t = blockIdx.x * 4 + wave;
    int src = gather ? win_to_img_row(t) : t;
    const float* xr = x + (size_t)src * 512 + lane * 8;
    float4 a = *(const float4*)xr;
    float4 c = *(const float4*)(xr + 4);
    float s = a.x + a.y + a.z + a.w + c.x + c.y + c.z + c.w;
    float s2 = a.x*a.x + a.y*a.y + a.z*a.z + a.w*a.w
             + c.x*c.x + c.y*c.y + c.z*c.z + c.w*c.w;
#pragma unroll
    for (int off = 32; off; off >>= 1) { s += __shfl_down(s, off); s2 += __shfl_down(s2, off); }
    s = __shfl(s, 0); s2 = __shfl(s2, 0);
    float mu = s * (1.f / 512.f);
    float var = s2 * (1.f / 512.f) - mu * mu;
    float rs = rsqrtf(var + 1e-5f);
    int col = lane * 8;
    float4 g0 = *(const float4*)(g + col), g1 = *(const float4*)(g + col + 4);
    float4 b0 = *(const float4*)(b + col), b1 = *(const float4*)(b + col + 4);
    u16 r[8];
    r[0] = f2bf((a.x - mu) * rs * g0.x + b0.x);
    r[1] = f2bf((a.y - mu) * rs * g0.y + b0.y);
    r[2] = f2bf((a.z - mu) * rs * g0.z + b0.z);
    r[3] = f2bf((a.w - mu) * rs * g0.w + b0.w);
    r[4] = f2bf((c.x - mu) * rs * g1.x + b1.x);
    r[5] = f2bf((c.y - mu) * rs * g1.y + b1.y);
    r[6] = f2bf((c.z - mu) * rs * g1.z + b1.z);
    r[7] = f2bf((c.w - mu) * rs * g1.w + b1.w);
    *(uint4*)(out + (size_t)t * 512 + col) = *(const uint4*)r;
}

__global__ __launch_bounds__(256) void transpose_k(
    const float* __restrict__ W, u16* __restrict__ WT, int K, int N)
{
    int f = blockIdx.x * 256 + threadIdx.x;
    int n = f % N, kc = f / N;
    if (kc >= (K >> 3)) return;
    int k0 = kc << 3;
    u16 r[8];
#pragma unroll
    for (int j = 0; j < 8; ++j) r[j] = f2bf(W[(size_t)(k0 + j) * N + n]);
    *(uint4*)(WT + (size_t)n * K + k0) = *(const uint4*)r;
}

// ---------------------------------------------------------------------------
// Direct-from-global MFMA GEMM: 128x128 tile, 4 waves, 16x16x32 bf16.
// Operand fragments loaded straight to VGPRs (b128 loads, L2-served).
// No LDS, no barriers -> compiler pipelines loads across the unrolled K-loop.
// ASRC: 0 plain bf16 A[lda] | 3 bf16 qkv-slice gather (k-step == one head).
// ---------------------------------------------------------------------------
enum { M_QKV = 0, M_PROJ = 1, M_GELU = 2, M_FINAL = 3 };

template <int MODE, int ASRC>
__global__ __launch_bounds__(256, 3) void gemm_direct(
    const u16* __restrict__ A, int lda,
    const u16* __restrict__ BT, int ldb,
    const float* __restrict__ bias,
    void* __restrict__ outp, const float* __restrict__ auxf, int K)
{
    int tid = threadIdx.x;
    int bm = blockIdx.y * 128, bn = blockIdx.x * 128;
    int wave = tid >> 6, lane = tid & 63;
    int quad = lane >> 4, lr = lane & 15;
    int wm = (wave >> 1) * 64, wn = (wave & 1) * 64;

    // per-lane base pointers for the 4 row-tiles of A and B fragments
    const u16* aP[4];
    const u16* bP[4];
    size_t aStep;                     // address advance per k-step (32 k)
#pragma unroll
    for (int t = 0; t < 4; ++t) {
        if constexpr (ASRC == 0) {
            aP[t] = A + (size_t)(bm + wm + t * 16 + lr) * lda + quad * 8;
        } else {  // qkv slice: [ (win*16 + head) * 2048 + tok*32 + d ]
            int row = bm + wm + t * 16 + lr;
            aP[t] = A + (size_t)((row >> 6) << 4) * 2048 + (row & 63) * 32 + quad * 8;
        }
        bP[t] = BT + (size_t)(bn + wn + t * 16 + lr) * ldb + quad * 8;
    }
    aStep = (ASRC == 0) ? 32 : 2048;

    floatx4 acc[4][4] = {};

#pragma unroll 8
    for (int ks = 0; ks < K / 32; ++ks) {
        short8 af[4], bv[4];
#pragma unroll
        for (int t = 0; t < 4; ++t) {
            af[t] = *(const short8*)(aP[t] + (size_t)ks * aStep);
            bv[t] = *(const short8*)(bP[t] + (size_t)ks * 32);
        }
#pragma unroll
        for (int mt = 0; mt < 4; ++mt)
#pragma unroll
            for (int nt = 0; nt < 4; ++nt)
                acc[mt][nt] = __builtin_amdgcn_mfma_f32_16x16x32_bf16(
                    af[mt], bv[nt], acc[mt][nt], 0, 0, 0);
    }

#pragma unroll
    for (int mt = 0; mt < 4; ++mt) {
#pragma unroll
        for (int nt = 0; nt < 4; ++nt) {
            int m0 = bm + wm + mt * 16 + quad * 4;
            int n = bn + wn + nt * 16 + lr;
#pragma unroll
            for (int i = 0; i < 4; ++i) {
                int m = m0 + i;
                float v = acc[mt][nt][i];
                if constexpr (MODE == M_QKV) {
                    v += bias[n];
                    int sel = n >> 9, head = (n >> 5) & 15, d = n & 31;
                    int wh = (m >> 6) * 16 + head, tok = m & 63;
                    ((u16*)outp)[(size_t)sel * 16777216 + (size_t)wh * 2048 + tok * 32 + d] = f2bf(v);
                } else if constexpr (MODE == M_PROJ) {
                    size_t idx = (size_t)win_to_img_row(m) * 512 + n;
                    ((float*)outp)[idx] = v + bias[n] + auxf[idx];
                } else if constexpr (MODE == M_GELU) {
                    v += bias[n];
                    float gel = 0.5f * v * (1.0f + erff(v * 0.70710678118654752f));
                    ((u16*)outp)[(size_t)m * 2048 + n] = f2bf(gel);
                } else { // M_FINAL: outp = xres f32, read-modify-write
                    size_t idx = (size_t)m * 512 + n;
                    float* o = (float*)outp;
                    o[idx] = o[idx] + v + bias[n];
                }
            }
        }
    }
}

// ---------------------------------------------------------------------------
// MFMA attention (unchanged): block = 4 waves = 4 windows x 1 head.
// ---------------------------------------------------------------------------
__global__ __launch_bounds__(256) void attn_mfma(
    const u16* __restrict__ qkv, const float* __restrict__ table,
    u16* __restrict__ outp)
{
    __shared__ __align__(8) u16 PT[4][64 * 76];
    __shared__ float blds[225];

    int w = threadIdx.x >> 6, lane = threadIdx.x & 63;
    int head = blockIdx.x & 15, win = ((blockIdx.x >> 4) << 2) + w;
    int wh = (win << 4) + head;
    int quad = lane >> 4, lr = lane & 15;
    const u16* qb = qkv + (size_t)wh * 2048;
    const u16* kb = qb + 16777216;
    const u16* vb = qb + 33554432;
    u16* PTw = PT[w];

    for (int i = threadIdx.x; i < 225; i += 256) blds[i] = table[i * 16 + head];
    __syncthreads();

    short8 qf[4], kf[4];
#pragma unroll
    for (int t = 0; t < 4; ++t) {
        qf[t] = *(const short8*)(qb + (t * 16 + lr) * 32 + quad * 8);
        kf[t] = *(const short8*)(kb + (t * 16 + lr) * 32 + quad * 8);
    }
    floatx4 s[4][4] = {};
#pragma unroll
    for (int mi = 0; mi < 4; ++mi)
#pragma unroll
        for (int ni = 0; ni < 4; ++ni)
            s[mi][ni] = __builtin_amdgcn_mfma_f32_16x16x32_bf16(qf[mi], kf[ni], s[mi][ni], 0, 0, 0);

    short8 vf[2][2];
#pragma unroll
    for (int ks = 0; ks < 2; ++ks)
#pragma unroll
        for (int nd = 0; nd < 2; ++nd)
#pragma unroll
            for (int j = 0; j < 8; ++j)
                vf[ks][nd][j] = (short)vb[(ks * 32 + quad * 8 + j) * 32 + nd * 16 + lr];

    int wr = (win >> 3) & 7, wc = win & 7;
    int rj[4], cj[4], regj[4];
#pragma unroll
    for (int ni = 0; ni < 4; ++ni) {
        int kj = ni * 16 + lr;
        rj[ni] = kj >> 3; cj[ni] = kj & 7;
        int hJ = wr * 8 + rj[ni], wJ = wc * 8 + cj[ni];
        regj[ni] = (hJ < 56 ? 0 : (hJ < 60 ? 1 : 2)) * 3 + (wJ < 56 ? 0 : (wJ < 60 ? 1 : 2));
    }
    float rm[4][4], linv[4][4];
#pragma unroll
    for (int mi = 0; mi < 4; ++mi) {
#pragma unroll
        for (int i = 0; i < 4; ++i) {
            int qi = mi * 16 + quad * 4 + i;
            int ri = qi >> 3, ci = qi & 7;
            int hI = wr * 8 + ri, wI = wc * 8 + ci;
            int regi = (hI < 56 ? 0 : (hI < 60 ? 1 : 2)) * 3 + (wI < 56 ? 0 : (wI < 60 ? 1 : 2));
            float mx = -1e30f;
#pragma unroll
            for (int ni = 0; ni < 4; ++ni) {
                float v = s[mi][ni][i] * 0.17677669529663687f
                        + blds[(ri - rj[ni] + 7) * 15 + (ci - cj[ni] + 7)];
                if (regj[ni] != regi) v -= 100.f;
                s[mi][ni][i] = v;
                mx = fmaxf(mx, v);
            }
            rm[mi][i] = mx;
        }
    }
#pragma unroll
    for (int mi = 0; mi < 4; ++mi)
#pragma unroll
        for (int i = 0; i < 4; ++i) {
            float mx = rm[mi][i];
#pragma unroll
            for (int msk = 1; msk < 16; msk <<= 1) mx = fmaxf(mx, __shfl_xor(mx, msk));
            float sum = 0.f;
#pragma unroll
            for (int ni = 0; ni < 4; ++ni) {
                float e = __expf(s[mi][ni][i] - mx);
                s[mi][ni][i] = e;
                sum += e;
            }
#pragma unroll
            for (int msk = 1; msk < 16; msk <<= 1) sum += __shfl_xor(sum, msk);
            linv[mi][i] = 1.f / sum;
        }

#pragma unroll
    for (int mi = 0; mi < 4; ++mi)
#pragma unroll
        for (int ni = 0; ni < 4; ++ni) {
            unsigned lo = (unsigned)f2bf(s[mi][ni][0]) | ((unsigned)f2bf(s[mi][ni][1]) << 16);
            unsigned hi = (unsigned)f2bf(s[mi][ni][2]) | ((unsigned)f2bf(s[mi][ni][3]) << 16);
            uint2 pk = make_uint2(lo, hi);
            *(uint2*)(PTw + (ni * 16 + lr) * 76 + mi * 16 + quad * 4) = pk;
        }
    __syncthreads();

    floatx4 o[4][2] = {};
#pragma unroll
    for (int mi = 0; mi < 4; ++mi) {
#pragma unroll
        for (int ks = 0; ks < 2; ++ks) {
            short8 pa;
#pragma unroll
            for (int j = 0; j < 8; ++j)
                pa[j] = (short)PTw[(ks * 32 + quad * 8 + j) * 76 + mi * 16 + lr];
#pragma unroll
            for (int nd = 0; nd < 2; ++nd)
                o[mi][nd] = __builtin_amdgcn_mfma_f32_16x16x32_bf16(pa, vf[ks][nd], o[mi][nd], 0, 0, 0);
        }
    }
    u16* ob = outp + (size_t)wh * 2048;
#pragma unroll
    for (int mi = 0; mi < 4; ++mi)
#pragma unroll
        for (int nd = 0; nd < 2; ++nd)
#pragma unroll
            for (int i = 0; i < 4; ++i) {
                int qi = mi * 16 + quad * 4 + i;
                ob[qi * 32 + nd * 16 + lr] = f2bf(o[mi][nd][i] * linv[mi][i]);
            }
}

// ---------------------------------------------------------------------------
extern "C" void kernel_launch(void* const* d_in, const int* in_sizes, int n_in,
                              void* d_out, int out_size, void* d_ws, size_t ws_size,
                              hipStream_t stream)
{
    (void)in_sizes; (void)n_in; (void)out_size; (void)ws_size;
    const float* x      = (const float*)d_in[0];
    const float* n1g    = (const float*)d_in[2];
    const float* n1b    = (const float*)d_in[3];
    const float* qkv_w  = (const float*)d_in[4];
    const float* qkv_b  = (const float*)d_in[5];
    const float* table  = (const float*)d_in[6];
    const float* proj_w = (const float*)d_in[7];
    const float* proj_b = (const float*)d_in[8];
    const float* n2g    = (const float*)d_in[9];
    const float* n2b    = (const float*)d_in[10];
    const float* fc1_w  = (const float*)d_in[11];
    const float* fc1_b  = (const float*)d_in[12];
    const float* fc2_w  = (const float*)d_in[13];
    const float* fc2_b  = (const float*)d_in[14];
    float* out = (float*)d_out;
    char* ws = (char*)d_ws;

    u16* qkvT  = (u16*)ws;                  // 786432
    u16* projT = qkvT + 786432;             // 262144
    u16* fc1T  = projT + 262144;            // 1048576
    u16* fc2T  = fc1T + 1048576;            // 1048576 (ends 6,291,456 B)
    u16* q    = (u16*)(ws + 8388608);       // q,k,v 3x32MB (ends 104 MB)
    u16* h2   = q;                          // overlays q after proj
    u16* gbuf = q + 16777216;               // 64 MB over k+v (dead post-attn)
    u16* xw   = (u16*)d_out;                // LN1+shift bf16, dead before proj

    transpose_k<<<384, 256, 0, stream>>>(qkv_w, qkvT, 512, 1536);
    transpose_k<<<128, 256, 0, stream>>>(proj_w, projT, 512, 512);
    transpose_k<<<512, 256, 0, stream>>>(fc1_w, fc1T, 512, 2048);
    transpose_k<<<512, 256, 0, stream>>>(fc2_w, fc2T, 2048, 512);

    // LN1 + shift/window gather -> xw (in d_out)
    ln_fused<<<8192, 256, 0, stream>>>(x, n1g, n1b, xw, 1);
    // QKV from xw
    gemm_direct<M_QKV, 0><<<dim3(12, 256), 256, 0, stream>>>(
        xw, 512, qkvT, 512, qkv_b, q, nullptr, 512);
    attn_mfma<<<2048, 256, 0, stream>>>(q, table, q);
    // proj + reverse-shift scatter + residual -> d_out (overwrites xw fully)
    gemm_direct<M_PROJ, 3><<<dim3(4, 256), 256, 0, stream>>>(
        q, 0, projT, 512, proj_b, out, x, 512);
    // LN2 -> h2
    ln_fused<<<8192, 256, 0, stream>>>(out, n2g, n2b, h2, 0);
    for (int mc = 0; mc < 2; ++mc) {
        gemm_direct<M_GELU, 0><<<dim3(16, 128), 256, 0, stream>>>(
            h2 + (size_t)mc * 16384 * 512, 512, fc1T, 512, fc1_b,
            gbuf, nullptr, 512);
        gemm_direct<M_FINAL, 0><<<dim3(4, 128), 256, 0, stream>>>(
            gbuf, 2048, fc2T, 2048, fc2_b,
            out + (size_t)mc * 16384 * 512, nullptr, 2048);
    }
}

// Round 6
// 545.502 us; speedup vs baseline: 1.7916x; 1.7916x over previous
//
#include <hip/hip_runtime.h>
#include <cstddef>
#include <cstdint>

// ---------------------------------------------------------------------------
// Swin block. f32 in/out; internal bf16 MFMA. B=8 H=W=64 DIM=512 NH=16 HD=32.
// GEMM: 128x128 tile, LDS chunk-major staging with COALESCED manual loads
// (global_load_dwordx4 -> ds_write_b128; consecutive lanes = consecutive 16B).
// ws: [0,6.3M) bf16 weights | q[8,40) k[40,72) v[72,104) MB
//     h2 overlays q after proj; gbuf (2x 16384x2048 bf16) overlays k+v.
// xw (LN1+shift, bf16 32MB) lives in d_out (dead until proj overwrites it).
// ---------------------------------------------------------------------------

typedef unsigned short u16;
typedef __attribute__((ext_vector_type(8))) short short8;
typedef __attribute__((ext_vector_type(4))) float floatx4;

__device__ __forceinline__ float bf2f(u16 u) {
    union { float f; unsigned i; } w; w.i = ((unsigned)u) << 16; return w.f;
}
__device__ __forceinline__ u16 f2bf(float f) {
    union { float f; unsigned i; } w; w.f = f;
    unsigned r = w.i + 0x7FFF + ((w.i >> 16) & 1);   // RNE
    return (u16)(r >> 16);
}

__device__ __forceinline__ int win_to_img_row(int t) {
    int win = t >> 6, n = t & 63;
    int b = win >> 6, wr = (win >> 3) & 7, wc = win & 7;
    int h = ((wr << 3) + (n >> 3) + 4) & 63;
    int w = ((wc << 3) + (n & 7) + 4) & 63;
    return (b << 12) + (h << 6) + w;
}

// ---------------------------------------------------------------------------
// Fused LayerNorm: one wave per 512-dim row, single pass.
// gather=1: row t reads shifted/windowed source row.
// ---------------------------------------------------------------------------
__global__ __launch_bounds__(256) void ln_fused(
    const float* __restrict__ x, const float* __restrict__ g,
    const float* __restrict__ b, u16* __restrict__ out, int gather)
{
    int wave = threadIdx.x >> 6, lane = threadIdx.x & 63;
    int t = blockIdx.x * 4 + wave;
    int src = gather ? win_to_img_row(t) : t;
    const float* xr = x + (size_t)src * 512 + lane * 8;
    float4 a = *(const float4*)xr;
    float4 c = *(const float4*)(xr + 4);
    float s = a.x + a.y + a.z + a.w + c.x + c.y + c.z + c.w;
    float s2 = a.x*a.x + a.y*a.y + a.z*a.z + a.w*a.w
             + c.x*c.x + c.y*c.y + c.z*c.z + c.w*c.w;
#pragma unroll
    for (int off = 32; off; off >>= 1) { s += __shfl_down(s, off); s2 += __shfl_down(s2, off); }
    s = __shfl(s, 0); s2 = __shfl(s2, 0);
    float mu = s * (1.f / 512.f);
    float var = s2 * (1.f / 512.f) - mu * mu;
    float rs = rsqrtf(var + 1e-5f);
    int col = lane * 8;
    float4 g0 = *(const float4*)(g + col), g1 = *(const float4*)(g + col + 4);
    float4 b0 = *(const float4*)(b + col), b1 = *(const float4*)(b + col + 4);
    u16 r[8];
    r[0] = f2bf((a.x - mu) * rs * g0.x + b0.x);
    r[1] = f2bf((a.y - mu) * rs * g0.y + b0.y);
    r[2] = f2bf((a.z - mu) * rs * g0.z + b0.z);
    r[3] = f2bf((a.w - mu) * rs * g0.w + b0.w);
    r[4] = f2bf((c.x - mu) * rs * g1.x + b1.x);
    r[5] = f2bf((c.y - mu) * rs * g1.y + b1.y);
    r[6] = f2bf((c.z - mu) * rs * g1.z + b1.z);
    r[7] = f2bf((c.w - mu) * rs * g1.w + b1.w);
    *(uint4*)(out + (size_t)t * 512 + col) = *(const uint4*)r;
}

__global__ __launch_bounds__(256) void transpose_k(
    const float* __restrict__ W, u16* __restrict__ WT, int K, int N)
{
    int f = blockIdx.x * 256 + threadIdx.x;
    int n = f % N, kc = f / N;
    if (kc >= (K >> 3)) return;
    int k0 = kc << 3;
    u16 r[8];
#pragma unroll
    for (int j = 0; j < 8; ++j) r[j] = f2bf(W[(size_t)(k0 + j) * N + n]);
    *(uint4*)(WT + (size_t)n * K + k0) = *(const uint4*)r;
}

// ---------------------------------------------------------------------------
// MFMA GEMM: 128x128 tile, BK=64, chunk-major LDS (stride 1032 u16 = 2064 B):
// element (row, k=c*8+j) at [c*1032 + row*8 + j]. Staging: f = l*256+tid with
// c = f&7 fastest -> 8 consecutive lanes read 8 consecutive 16B chunks of one
// row (coalesced 128B), wave covers 8 contiguous rows (1KB). LDS writes:
// lane banks 4c..4c+3, conflict-free. Fragment b128 reads conflict-free.
// ASRC: 0 plain bf16 A[lda] | 3 bf16 qkv-slice gather.
// ---------------------------------------------------------------------------
enum { M_QKV = 0, M_PROJ = 1, M_GELU = 2, M_FINAL = 3 };

template <int MODE, int ASRC>
__global__ __launch_bounds__(256, 4) void gemm_bt(
    const u16* __restrict__ A, int lda,
    const u16* __restrict__ BT, int ldb,
    const float* __restrict__ bias,
    void* __restrict__ outp, const float* __restrict__ auxf, int K)
{
    __shared__ __align__(16) u16 As[8 * 1032];
    __shared__ __align__(16) u16 Bs[8 * 1032];

    int tid = threadIdx.x;
    int bm = blockIdx.y * 128, bn = blockIdx.x * 128;
    int wave = tid >> 6, lane = tid & 63;
    int quad = lane >> 4, lr = lane & 15;
    int wm = (wave >> 1) * 64, wn = (wave & 1) * 64;

    floatx4 acc[4][4] = {};

    for (int k0 = 0; k0 < K; k0 += 64) {
        uint4 aR[4], bR[4];
#pragma unroll
        for (int l = 0; l < 4; ++l) {
            int f = (l << 8) + tid;            // 0..1023
            int row = f >> 3, c = f & 7;
            int kk = k0 + c * 8;
            bR[l] = *(const uint4*)(BT + (size_t)(bn + row) * ldb + kk);
            if constexpr (ASRC == 0) {
                aR[l] = *(const uint4*)(A + (size_t)(bm + row) * lda + kk);
            } else {  // qkv-slice gather: [ (win*16+head)*2048 + tok*32 + d ]
                int m = bm + row;
                aR[l] = *(const uint4*)(A + (size_t)(((m >> 6) << 4) + (kk >> 5)) * 2048
                                          + (m & 63) * 32 + (kk & 31));
            }
        }
#pragma unroll
        for (int l = 0; l < 4; ++l) {
            int f = (l << 8) + tid;
            int row = f >> 3, c = f & 7;
            *(uint4*)(Bs + c * 1032 + row * 8) = bR[l];
            *(uint4*)(As + c * 1032 + row * 8) = aR[l];
        }
        __syncthreads();
#pragma unroll
        for (int step = 0; step < 2; ++step) {
            short8 af[4], bv[4];
#pragma unroll
            for (int t = 0; t < 4; ++t) {
                int kc = step * 4 + quad;
                af[t] = *(const short8*)(As + kc * 1032 + (wm + t * 16 + lr) * 8);
                bv[t] = *(const short8*)(Bs + kc * 1032 + (wn + t * 16 + lr) * 8);
            }
#pragma unroll
            for (int mt = 0; mt < 4; ++mt)
#pragma unroll
                for (int nt = 0; nt < 4; ++nt)
                    acc[mt][nt] = __builtin_amdgcn_mfma_f32_16x16x32_bf16(
                        af[mt], bv[nt], acc[mt][nt], 0, 0, 0);
        }
        __syncthreads();
    }

#pragma unroll
    for (int mt = 0; mt < 4; ++mt) {
#pragma unroll
        for (int nt = 0; nt < 4; ++nt) {
            int m0 = bm + wm + mt * 16 + quad * 4;
            int n = bn + wn + nt * 16 + lr;
#pragma unroll
            for (int i = 0; i < 4; ++i) {
                int m = m0 + i;
                float v = acc[mt][nt][i];
                if constexpr (MODE == M_QKV) {
                    v += bias[n];
                    int sel = n >> 9, head = (n >> 5) & 15, d = n & 31;
                    int wh = (m >> 6) * 16 + head, tok = m & 63;
                    ((u16*)outp)[(size_t)sel * 16777216 + (size_t)wh * 2048 + tok * 32 + d] = f2bf(v);
                } else if constexpr (MODE == M_PROJ) {
                    size_t idx = (size_t)win_to_img_row(m) * 512 + n;
                    ((float*)outp)[idx] = v + bias[n] + auxf[idx];
                } else if constexpr (MODE == M_GELU) {
                    v += bias[n];
                    float gel = 0.5f * v * (1.0f + erff(v * 0.70710678118654752f));
                    ((u16*)outp)[(size_t)m * 2048 + n] = f2bf(gel);
                } else { // M_FINAL: outp = xres f32, read-modify-write
                    size_t idx = (size_t)m * 512 + n;
                    float* o = (float*)outp;
                    o[idx] = o[idx] + v + bias[n];
                }
            }
        }
    }
}

// ---------------------------------------------------------------------------
// MFMA attention (unchanged): block = 4 waves = 4 windows x 1 head.
// ---------------------------------------------------------------------------
__global__ __launch_bounds__(256) void attn_mfma(
    const u16* __restrict__ qkv, const float* __restrict__ table,
    u16* __restrict__ outp)
{
    __shared__ __align__(8) u16 PT[4][64 * 76];
    __shared__ float blds[225];

    int w = threadIdx.x >> 6, lane = threadIdx.x & 63;
    int head = blockIdx.x & 15, win = ((blockIdx.x >> 4) << 2) + w;
    int wh = (win << 4) + head;
    int quad = lane >> 4, lr = lane & 15;
    const u16* qb = qkv + (size_t)wh * 2048;
    const u16* kb = qb + 16777216;
    const u16* vb = qb + 33554432;
    u16* PTw = PT[w];

    for (int i = threadIdx.x; i < 225; i += 256) blds[i] = table[i * 16 + head];
    __syncthreads();

    short8 qf[4], kf[4];
#pragma unroll
    for (int t = 0; t < 4; ++t) {
        qf[t] = *(const short8*)(qb + (t * 16 + lr) * 32 + quad * 8);
        kf[t] = *(const short8*)(kb + (t * 16 + lr) * 32 + quad * 8);
    }
    floatx4 s[4][4] = {};
#pragma unroll
    for (int mi = 0; mi < 4; ++mi)
#pragma unroll
        for (int ni = 0; ni < 4; ++ni)
            s[mi][ni] = __builtin_amdgcn_mfma_f32_16x16x32_bf16(qf[mi], kf[ni], s[mi][ni], 0, 0, 0);

    short8 vf[2][2];
#pragma unroll
    for (int ks = 0; ks < 2; ++ks)
#pragma unroll
        for (int nd = 0; nd < 2; ++nd)
#pragma unroll
            for (int j = 0; j < 8; ++j)
                vf[ks][nd][j] = (short)vb[(ks * 32 + quad * 8 + j) * 32 + nd * 16 + lr];

    int wr = (win >> 3) & 7, wc = win & 7;
    int rj[4], cj[4], regj[4];
#pragma unroll
    for (int ni = 0; ni < 4; ++ni) {
        int kj = ni * 16 + lr;
        rj[ni] = kj >> 3; cj[ni] = kj & 7;
        int hJ = wr * 8 + rj[ni], wJ = wc * 8 + cj[ni];
        regj[ni] = (hJ < 56 ? 0 : (hJ < 60 ? 1 : 2)) * 3 + (wJ < 56 ? 0 : (wJ < 60 ? 1 : 2));
    }
    float rm[4][4], linv[4][4];
#pragma unroll
    for (int mi = 0; mi < 4; ++mi) {
#pragma unroll
        for (int i = 0; i < 4; ++i) {
            int qi = mi * 16 + quad * 4 + i;
            int ri = qi >> 3, ci = qi & 7;
            int hI = wr * 8 + ri, wI = wc * 8 + ci;
            int regi = (hI < 56 ? 0 : (hI < 60 ? 1 : 2)) * 3 + (wI < 56 ? 0 : (wI < 60 ? 1 : 2));
            float mx = -1e30f;
#pragma unroll
            for (int ni = 0; ni < 4; ++ni) {
                float v = s[mi][ni][i] * 0.17677669529663687f
                        + blds[(ri - rj[ni] + 7) * 15 + (ci - cj[ni] + 7)];
                if (regj[ni] != regi) v -= 100.f;
                s[mi][ni][i] = v;
                mx = fmaxf(mx, v);
            }
            rm[mi][i] = mx;
        }
    }
#pragma unroll
    for (int mi = 0; mi < 4; ++mi)
#pragma unroll
        for (int i = 0; i < 4; ++i) {
            float mx = rm[mi][i];
#pragma unroll
            for (int msk = 1; msk < 16; msk <<= 1) mx = fmaxf(mx, __shfl_xor(mx, msk));
            float sum = 0.f;
#pragma unroll
            for (int ni = 0; ni < 4; ++ni) {
                float e = __expf(s[mi][ni][i] - mx);
                s[mi][ni][i] = e;
                sum += e;
            }
#pragma unroll
            for (int msk = 1; msk < 16; msk <<= 1) sum += __shfl_xor(sum, msk);
            linv[mi][i] = 1.f / sum;
        }

#pragma unroll
    for (int mi = 0; mi < 4; ++mi)
#pragma unroll
        for (int ni = 0; ni < 4; ++ni) {
            unsigned lo = (unsigned)f2bf(s[mi][ni][0]) | ((unsigned)f2bf(s[mi][ni][1]) << 16);
            unsigned hi = (unsigned)f2bf(s[mi][ni][2]) | ((unsigned)f2bf(s[mi][ni][3]) << 16);
            uint2 pk = make_uint2(lo, hi);
            *(uint2*)(PTw + (ni * 16 + lr) * 76 + mi * 16 + quad * 4) = pk;
        }
    __syncthreads();

    floatx4 o[4][2] = {};
#pragma unroll
    for (int mi = 0; mi < 4; ++mi) {
#pragma unroll
        for (int ks = 0; ks < 2; ++ks) {
            short8 pa;
#pragma unroll
            for (int j = 0; j < 8; ++j)
                pa[j] = (short)PTw[(ks * 32 + quad * 8 + j) * 76 + mi * 16 + lr];
#pragma unroll
            for (int nd = 0; nd < 2; ++nd)
                o[mi][nd] = __builtin_amdgcn_mfma_f32_16x16x32_bf16(pa, vf[ks][nd], o[mi][nd], 0, 0, 0);
        }
    }
    u16* ob = outp + (size_t)wh * 2048;
#pragma unroll
    for (int mi = 0; mi < 4; ++mi)
#pragma unroll
        for (int nd = 0; nd < 2; ++nd)
#pragma unroll
            for (int i = 0; i < 4; ++i) {
                int qi = mi * 16 + quad * 4 + i;
                ob[qi * 32 + nd * 16 + lr] = f2bf(o[mi][nd][i] * linv[mi][i]);
            }
}

// ---------------------------------------------------------------------------
extern "C" void kernel_launch(void* const* d_in, const int* in_sizes, int n_in,
                              void* d_out, int out_size, void* d_ws, size_t ws_size,
                              hipStream_t stream)
{
    (void)in_sizes; (void)n_in; (void)out_size; (void)ws_size;
    const float* x      = (const float*)d_in[0];
    const float* n1g    = (const float*)d_in[2];
    const float* n1b    = (const float*)d_in[3];
    const float* qkv_w  = (const float*)d_in[4];
    const float* qkv_b  = (const float*)d_in[5];
    const float* table  = (const float*)d_in[6];
    const float* proj_w = (const float*)d_in[7];
    const float* proj_b = (const float*)d_in[8];
    const float* n2g    = (const float*)d_in[9];
    const float* n2b    = (const float*)d_in[10];
    const float* fc1_w  = (const float*)d_in[11];
    const float* fc1_b  = (const float*)d_in[12];
    const float* fc2_w  = (const float*)d_in[13];
    const float* fc2_b  = (const float*)d_in[14];
    float* out = (float*)d_out;
    char* ws = (char*)d_ws;

    u16* qkvT  = (u16*)ws;                  // 786432
    u16* projT = qkvT + 786432;             // 262144
    u16* fc1T  = projT + 262144;            // 1048576
    u16* fc2T  = fc1T + 1048576;            // 1048576 (ends 6,291,456 B)
    u16* q    = (u16*)(ws + 8388608);       // q,k,v 3x32MB (ends 104 MB)
    u16* h2   = q;                          // overlays q after proj
    u16* gbuf = q + 16777216;               // 64 MB over k+v (dead post-attn)
    u16* xw   = (u16*)d_out;                // LN1+shift bf16, dead before proj

    transpose_k<<<384, 256, 0, stream>>>(qkv_w, qkvT, 512, 1536);
    transpose_k<<<128, 256, 0, stream>>>(proj_w, projT, 512, 512);
    transpose_k<<<512, 256, 0, stream>>>(fc1_w, fc1T, 512, 2048);
    transpose_k<<<512, 256, 0, stream>>>(fc2_w, fc2T, 2048, 512);

    // LN1 + shift/window gather -> xw (in d_out)
    ln_fused<<<8192, 256, 0, stream>>>(x, n1g, n1b, xw, 1);
    // QKV from xw
    gemm_bt<M_QKV, 0><<<dim3(12, 256), 256, 0, stream>>>(
        xw, 512, qkvT, 512, qkv_b, q, nullptr, 512);
    attn_mfma<<<2048, 256, 0, stream>>>(q, table, q);
    // proj + reverse-shift scatter + residual -> d_out (overwrites xw fully)
    gemm_bt<M_PROJ, 3><<<dim3(4, 256), 256, 0, stream>>>(
        q, 0, projT, 512, proj_b, out, x, 512);
    // LN2 -> h2
    ln_fused<<<8192, 256, 0, stream>>>(out, n2g, n2b, h2, 0);
    for (int mc = 0; mc < 2; ++mc) {
        gemm_bt<M_GELU, 0><<<dim3(16, 128), 256, 0, stream>>>(
            h2 + (size_t)mc * 16384 * 512, 512, fc1T, 512, fc1_b,
            gbuf, nullptr, 512);
        gemm_bt<M_FINAL, 0><<<dim3(4, 128), 256, 0, stream>>>(
            gbuf, 2048, fc2T, 2048, fc2_b,
            out + (size_t)mc * 16384 * 512, nullptr, 2048);
    }
}